// Round 4
// baseline (2346.984 us; speedup 1.0000x reference)
//
#include <hip/hip_runtime.h>

// BRITS-style recurrent imputation on MI355X.
// Partition: 256 blocks = 8 batch-tiles(16 rows) x 32 H-chunks(16 H each).
// Weights pre-packed to f16 MFMA B-fragments, persistent in VGPRs.
// R4: handshake flattened — per-chunk tag words (plain UC stores, no RMW),
//     all-wave independent polling (no syncthreads on the detect path),
//     gamma_h MFMA hoisted into the prefetch window, split MFMA acc chains,
//     distributed imputation stores, coalesced k_delta.

#define B_ 128
#define T_ 256
#define D_ 128
#define H_ 512

typedef _Float16 f16x8 __attribute__((ext_vector_type(8)));
typedef float    f32x4 __attribute__((ext_vector_type(4)));

// ---- workspace layout (bytes), total 12,116,992 (< R1-proven 20,497,408) ----
#define OFF_HBUF   0u          // f16 [2][128][512]        262144
#define OFF_TAG    262144u     // uint [8][32] @64B        16384
#define OFF_MSUM   278528u     // float [256]              1024
#define OFF_BG     279552u     // float [2048]             8192
#define OFF_WH     287744u     // f16 [8][16][64][8]       131072
#define OFF_WF     418816u     // f16 [8][4][64][8]        32768
#define OFF_WD     451584u     // f16 [32][4][64][8]       131072
#define OFF_GB     582656u     // f16 [32][4][24][64][8]   3145728
#define OFF_DBF    3728384u    // f16 [128][256][128]      8388608

__device__ __forceinline__ float sigm(float x)  { return __fdividef(1.0f, 1.0f + __expf(-x)); }
__device__ __forceinline__ float tanh_(float x) { return 1.0f - __fdividef(2.0f, __expf(2.0f*x) + 1.0f); }

// ---------------- pre-kernels ----------------

__global__ void k_zero(unsigned int* __restrict__ wsu, float* __restrict__ out){
  int id = blockIdx.x*256 + threadIdx.x;
  if (id < 69888) wsu[id] = 0u;     // hbuf + tags + msum
  if (id == 0) out[0] = 0.0f;
}

// msum[t] only (masks derived on the fly in brits_main)
__global__ void k_mask(const float* __restrict__ data, float* __restrict__ msum){
  int idx = blockIdx.x*256 + threadIdx.x;     // < 128*256*128
  float v = data[idx];
  bool m = (v == v);
  unsigned long long bal = __ballot(m);       // 64 lanes share one (b,t) row half
  if ((threadIdx.x & 63) == 0) {
    int t = (idx >> 7) & 255;
    atomicAdd(&msum[t], (float)__popcll(bal));
  }
}

// delta_calc, wave-cooperative: block = 1 wave = 64 t-values of one b.
// Stage 65 row-masks (128-bit each) via coalesced loads + ballot, then
// each lane scans its own t from LDS masks (exact reference semantics).
__global__ void k_delta(const float* __restrict__ data, _Float16* __restrict__ dbf){
  int b  = blockIdx.x >> 2;
  int t0 = (blockIdx.x & 3) * 64;
  int ln = threadIdx.x;                       // 0..63
  __shared__ unsigned long long rm[65][2];
  for (int r = 0; r < 65; ++r) {
    int t = t0 - 1 + r;
    unsigned long long m0 = 0, m1 = 0;
    if (t >= 0) {
      const float* row = data + ((size_t)b*256 + t)*128;
      float a = row[ln], c = row[64 + ln];
      m0 = __ballot(a == a);
      m1 = __ballot(c == c);
    }
    if (ln == 0) { rm[r][0] = m0; rm[r][1] = m1; }
  }
  __syncthreads();
  int t = t0 + ln;
  _Float16* orow = dbf + ((size_t)b*256 + t)*128;
  if (t == 0) {
    f16x8 z;
    #pragma unroll
    for (int i=0;i<8;i++) z[i] = (_Float16)0.0f;
    #pragma unroll
    for (int k=0;k<16;k++) ((f16x8*)orow)[k] = z;
    return;
  }
  unsigned long long mp0 = rm[ln][0],   mp1 = rm[ln][1];
  unsigned long long mt0 = rm[ln+1][0], mt1 = rm[ln+1][1];
  float carry = 0.0f;
  for (int g = 0; g < 16; ++g) {
    f16x8 v;
    #pragma unroll
    for (int j = 0; j < 8; ++j) {
      int d = g*8 + j;
      bool prevm = (d < 64)   ? ((mp0 >> d) & 1ull)        : ((mp1 >> (d-64)) & 1ull);
      int dm1 = (d - 1) & 127;
      bool leftm = (dm1 < 64) ? ((mt0 >> dm1) & 1ull)      : ((mt1 >> (dm1-64)) & 1ull);
      float val = (!prevm) ? (carry + 1.0f) : (leftm ? 1.0f : 0.0f);
      carry = val;
      v[j] = (_Float16)val;
    }
    ((f16x8*)orow)[g] = v;
  }
}

// Weight pre-pack into MFMA B-fragment order: [..][ks][lane][8], B[k][n]=W[n][k],
// n = lane&15, k = ks*32 + (lane>>4)*8 + j.
__global__ void k_pack_wh(const float* __restrict__ Wh, _Float16* __restrict__ dst){
  int id = blockIdx.x*256 + threadIdx.x;      // 65536 = [8][16][64][8]
  int j = id & 7, l = (id>>3)&63, ks = (id>>9)&15, nt = id>>13;
  int row = nt*16 + (l&15);
  int k   = ks*32 + ((l>>4)&3)*8 + j;
  dst[id] = (_Float16)Wh[row*512 + k];
}
__global__ void k_pack_wf(const float* __restrict__ Wf, _Float16* __restrict__ dst){
  int id = blockIdx.x*256 + threadIdx.x;      // 16384 = [8][4][64][8]
  int j = id & 7, l = (id>>3)&63, ks = (id>>9)&3, nt = id>>11;
  int row = nt*16 + (l&15);
  int k   = ks*32 + ((l>>4)&3)*8 + j;
  float v = (row == k) ? 0.0f : Wf[row*128 + k];   // off-diagonal mask
  dst[id] = (_Float16)v;
}
__global__ void k_pack_wd(const float* __restrict__ Wdh, _Float16* __restrict__ dst){
  int id = blockIdx.x*256 + threadIdx.x;      // 65536 = [32][4][64][8]
  int j = id & 7, l = (id>>3)&63, ks = (id>>9)&3, c = id>>11;
  int row = c*16 + (l&15);
  int k   = ks*32 + ((l>>4)&3)*8 + j;
  dst[id] = (_Float16)Wdh[row*128 + k];
}
__global__ void k_pack_gb(const float* __restrict__ W_ih, const float* __restrict__ W_hh,
                          _Float16* __restrict__ dst){
  int id = blockIdx.x*256 + threadIdx.x;      // 1572864 = [32][4][24][64][8]
  int j = id & 7, l = (id>>3)&63;
  int f = id>>9;
  int ks = f % 24; f /= 24;
  int g = f & 3, c = f >> 2;
  int rn = g*512 + c*16 + (l&15);
  int k  = ks*32 + ((l>>4)&3)*8 + j;          // inp K: [0,256)=[c_c,m], [256,768)=h
  float v = (k < 256) ? W_ih[rn*256 + k] : W_hh[rn*512 + (k-256)];
  dst[id] = (_Float16)v;
}
__global__ void k_pack_bias(const float* __restrict__ b_ih, const float* __restrict__ b_hh,
                            float* __restrict__ dst){
  int id = blockIdx.x*256 + threadIdx.x;      // 2048
  dst[id] = b_ih[id] + b_hh[id];
}

// ---------------- main persistent kernel ----------------
// grid 256 blocks (8 batch-tiles x 16 rows) x (32 chunks x 16 H), 256 threads.

__global__ __launch_bounds__(256, 1) void brits_main(
    const float* __restrict__ data,
    const float* __restrict__ bh,
    const float* __restrict__ bfv,
    const float* __restrict__ bdh,
    unsigned char* __restrict__ ws,
    float* __restrict__ out)
{
  const int bt  = blockIdx.x >> 5;    // batch tile 0..7
  const int ch  = blockIdx.x & 31;    // H chunk 0..31
  const int tid = threadIdx.x;
  const int wv  = tid >> 6;           // wave 0..3
  const int ln  = tid & 63;
  const int l15 = ln & 15;
  const int lq  = ln >> 4;

  _Float16*       hbuf = (_Float16*)(ws + OFF_HBUF);
  unsigned int*   tag  = (unsigned int*)(ws + OFF_TAG);
  const float*    msum = (const float*)(ws + OFF_MSUM);
  const float*    bgq  = (const float*)(ws + OFF_BG);
  const f16x8*    WhP  = (const f16x8*)(ws + OFF_WH);
  const f16x8*    WfP  = (const f16x8*)(ws + OFF_WF);
  const f16x8*    WdP  = (const f16x8*)(ws + OFF_WD);
  const f16x8*    GBP  = (const f16x8*)(ws + OFF_GB);
  const _Float16* dbf  = (const _Float16*)(ws + OFF_DBF);

  __shared__ __align__(16) _Float16 xcT[16][136];
  __shared__ __align__(16) _Float16 ccT[16][136];
  __shared__ __align__(8)  _Float16 hstg[16][16];   // h staging for 8B bypass stores
  __shared__ float gbuf[4][16][16];
  __shared__ float cst[16][16];
  __shared__ float invms[256];
  __shared__ float bh_s[128], bf_s[128], bdh_s[16], bg_s[4][16];
  __shared__ float red[256];

  invms[tid] = 1.0f / (msum[tid] + 1e-5f);
  if (tid < 128) { bh_s[tid] = bh[tid]; bf_s[tid] = bfv[tid]; }
  if (tid < 16)  bdh_s[tid] = bdh[ch*16 + tid];
  if (tid < 64)  bg_s[tid>>4][tid&15] = bgq[(tid>>4)*512 + ch*16 + (tid&15)];
  ((float*)cst)[tid] = 0.0f;
  __syncthreads();

  // ---- persistent weight fragments in VGPRs ----
  f16x8 WhB[2][16], WfB[2][4], GB[24], WdB[4];
  #pragma unroll
  for (int i=0;i<2;i++)
    #pragma unroll
    for (int ks=0;ks<16;ks++)
      WhB[i][ks] = WhP[((2*wv+i)*16 + ks)*64 + ln];
  #pragma unroll
  for (int i=0;i<2;i++)
    #pragma unroll
    for (int ks=0;ks<4;ks++)
      WfB[i][ks] = WfP[((2*wv+i)*4 + ks)*64 + ln];
  #pragma unroll
  for (int ks=0;ks<24;ks++)
    GB[ks] = GBP[((ch*4 + wv)*24 + ks)*64 + ln];
  #pragma unroll
  for (int ks=0;ks<4;ks++)
    WdB[ks] = WdP[(ch*4 + ks)*64 + ln];

  float loss_acc = 0.0f;
  const int rowg = bt*16;
  const unsigned int* mytag = tag + ((bt<<5) + (ln & 31))*16;

  #pragma unroll 1
  for (int t = 0; t < 256; ++t) {
    // ---- prefetch everything that doesn't depend on h(t) ----
    float xnv[2][4], mmv[2][4];
    #pragma unroll
    for (int i=0;i<2;i++){
      int col = (2*wv+i)*16 + l15;
      #pragma unroll
      for (int r=0;r<4;r++){
        float dv = data[((rowg + lq*4 + r)*256 + t)*128 + col];
        bool ok = (dv == dv);
        xnv[i][r] = ok ? dv : 0.0f;
        mmv[i][r] = ok ? 1.0f : 0.0f;
      }
    }
    f16x8 mA[4];
    {
      const float* mrow = data + ((size_t)(rowg + l15)*256 + t)*128 + lq*8;
      #pragma unroll
      for (int k=0;k<4;k++){
        float4 a0 = *(const float4*)(mrow + k*32);
        float4 a1 = *(const float4*)(mrow + k*32 + 4);
        f16x8 mv;
        mv[0] = (a0.x==a0.x)?(_Float16)1.0f:(_Float16)0.0f;
        mv[1] = (a0.y==a0.y)?(_Float16)1.0f:(_Float16)0.0f;
        mv[2] = (a0.z==a0.z)?(_Float16)1.0f:(_Float16)0.0f;
        mv[3] = (a0.w==a0.w)?(_Float16)1.0f:(_Float16)0.0f;
        mv[4] = (a1.x==a1.x)?(_Float16)1.0f:(_Float16)0.0f;
        mv[5] = (a1.y==a1.y)?(_Float16)1.0f:(_Float16)0.0f;
        mv[6] = (a1.z==a1.z)?(_Float16)1.0f:(_Float16)0.0f;
        mv[7] = (a1.w==a1.w)?(_Float16)1.0f:(_Float16)0.0f;
        mA[k] = mv;
      }
    }
    // gamma_h(t+1) pre-activation: h-independent, hoisted into the wait window
    f32x4 ga = {0.f,0.f,0.f,0.f};
    if (wv == 0 && t < 255) {
      f16x8 dA[4];
      #pragma unroll
      for (int k=0;k<4;k++)
        dA[k] = *(const f16x8*)(dbf + ((size_t)(rowg+l15)*256 + (t+1))*128 + k*32 + lq*8);
      #pragma unroll
      for (int k=0;k<4;k++)
        ga = __builtin_amdgcn_mfma_f32_16x16x32_f16(dA[k], WdB[k], ga, 0,0,0);
    }

    // ---- wait for h(t): every wave polls all 32 tags (no block barrier) ----
    if (t > 0) {
      for (;;) {
        bool ok = true;
        if (ln < 32)
          ok = __hip_atomic_load(mytag, __ATOMIC_RELAXED,
                                 __HIP_MEMORY_SCOPE_AGENT) >= (unsigned)t;
        if (__ballot(ok) == ~0ull) break;
        __builtin_amdgcn_s_sleep(1);
      }
    }

    // ---- h A-fragments via 8B bypassing atomic loads (fresh from IC) ----
    f16x8 hA[16];
    const _Float16* hb = hbuf + (size_t)(t&1)*65536 + (size_t)(rowg + l15)*512 + lq*8;
    #pragma unroll
    for (int ks=0;ks<16;ks++) {
      union { unsigned long long u[2]; f16x8 v; } cv;
      cv.u[0] = __hip_atomic_load((const unsigned long long*)(hb + ks*32),
                                  __ATOMIC_RELAXED, __HIP_MEMORY_SCOPE_AGENT);
      cv.u[1] = __hip_atomic_load((const unsigned long long*)(hb + ks*32 + 4),
                                  __ATOMIC_RELAXED, __HIP_MEMORY_SCOPE_AGENT);
      hA[ks] = cv.v;
    }

    // ---- x_h = sigmoid(h @ Wh^T + bh); loss1; x_c ----  (split acc chains)
    float xhv[2][4];
    float numer = 0.0f;
    #pragma unroll
    for (int i=0;i<2;i++){
      f32x4 a0 = {0.f,0.f,0.f,0.f}, a1 = {0.f,0.f,0.f,0.f};
      #pragma unroll
      for (int ks=0;ks<8;ks++){
        a0 = __builtin_amdgcn_mfma_f32_16x16x32_f16(hA[ks],   WhB[i][ks],   a0, 0,0,0);
        a1 = __builtin_amdgcn_mfma_f32_16x16x32_f16(hA[ks+8], WhB[i][ks+8], a1, 0,0,0);
      }
      int col = (2*wv+i)*16 + l15;
      float bhc = bh_s[col];
      #pragma unroll
      for (int r=0;r<4;r++){
        float s = sigm(a0[r] + a1[r] + bhc);
        xhv[i][r] = s;
        numer += fabsf(xnv[i][r] - s) * mmv[i][r];
        float xc = (mmv[i][r] > 0.f) ? xnv[i][r] : s;
        xcT[lq*4 + r][col] = (_Float16)xc;
      }
    }
    __syncthreads();

    // ---- z_h MFMAs + gate partials (h & m parts) interleaved ----
    f16x8 xcA[4];
    #pragma unroll
    for (int k=0;k<4;k++)
      xcA[k] = *(const f16x8*)(&xcT[l15][k*32 + lq*8]);
    f32x4 z0 = {0.f,0.f,0.f,0.f}, z1 = {0.f,0.f,0.f,0.f};
    #pragma unroll
    for (int ks=0;ks<4;ks++){
      z0 = __builtin_amdgcn_mfma_f32_16x16x32_f16(xcA[ks], WfB[0][ks], z0, 0,0,0);
      z1 = __builtin_amdgcn_mfma_f32_16x16x32_f16(xcA[ks], WfB[1][ks], z1, 0,0,0);
    }
    f32x4 g0 = {0.f,0.f,0.f,0.f}, g1 = {0.f,0.f,0.f,0.f};
    #pragma unroll
    for (int k=0;k<4;k++){
      g0 = __builtin_amdgcn_mfma_f32_16x16x32_f16(mA[k],   GB[4+k],  g0, 0,0,0);
      g1 = __builtin_amdgcn_mfma_f32_16x16x32_f16(hA[k+8], GB[16+k], g1, 0,0,0);
    }
    #pragma unroll
    for (int ks=0;ks<8;ks++)
      g0 = __builtin_amdgcn_mfma_f32_16x16x32_f16(hA[ks], GB[8+ks], g0, 0,0,0);
    #pragma unroll
    for (int ks=4;ks<8;ks++)
      g1 = __builtin_amdgcn_mfma_f32_16x16x32_f16(hA[ks+8], GB[16+ks], g1, 0,0,0);

    // ---- z_h epilogue: loss2, c_c, distributed imputation store ----
    #pragma unroll
    for (int i=0;i<2;i++){
      f32x4 a = (i==0) ? z0 : z1;
      int col = (2*wv+i)*16 + l15;
      float bfc = bf_s[col];
      bool mine = ((col >> 2) == ch);
      #pragma unroll
      for (int r=0;r<4;r++){
        float z = sigm(a[r] + bfc);
        numer += fabsf(xnv[i][r] - z) * mmv[i][r];
        float chv = fabsf(0.5f*z + 0.5f*xhv[i][r]);
        float cc  = (mmv[i][r] > 0.f) ? xnv[i][r] : chv;
        int row = lq*4 + r;
        ccT[row][col] = (_Float16)cc;
        if (mine) out[1 + ((size_t)(rowg+row)*256 + t)*128 + col] = cc;
      }
    }
    if (ch == 0) loss_acc += numer * invms[t];
    __syncthreads();

    // ---- gates: add c_c part, reduce, stash ----
    f16x8 ccA[4];
    #pragma unroll
    for (int k=0;k<4;k++)
      ccA[k] = *(const f16x8*)(&ccT[l15][k*32 + lq*8]);
    #pragma unroll
    for (int k=0;k<4;k++)
      g0 = __builtin_amdgcn_mfma_f32_16x16x32_f16(ccA[k], GB[k], g0, 0,0,0);
    #pragma unroll
    for (int r=0;r<4;r++) gbuf[wv][lq*4 + r][l15] = g0[r] + g1[r];
    __syncthreads();

    // ---- LSTM cell epilogue + gamma_h(t+1)-scaled h store + tag (wave 0) ----
    if (wv == 0) {
      #pragma unroll
      for (int r=0;r<4;r++){
        int row = lq*4 + r;
        float ii = gbuf[0][row][l15] + bg_s[0][l15];
        float ff = gbuf[1][row][l15] + bg_s[1][l15];
        float gg = gbuf[2][row][l15] + bg_s[2][l15];
        float oo = gbuf[3][row][l15] + bg_s[3][l15];
        float co = cst[row][l15];
        float cn = sigm(ff)*co + sigm(ii)*tanh_(gg);
        cst[row][l15] = cn;
        if (t < 255) {
          float hn = sigm(oo)*tanh_(cn);
          float gh = __expf(-fmaxf(ga[r] + bdh_s[l15], 0.0f));
          hstg[row][l15] = (_Float16)(hn * gh);
        }
      }
      if (t < 255) {
        // compiler barrier: hstg f16 writes must precede the u64 re-read
        __asm__ __volatile__("" ::: "memory");
        // 8B cache-bypassing stores straight to the coherence point
        int row2 = ln >> 2, c4 = (ln & 3) * 4;
        unsigned long long v = *(const unsigned long long*)&hstg[row2][c4];
        __hip_atomic_store(
            (unsigned long long*)(hbuf + (size_t)((t+1)&1)*65536
                                  + (size_t)(rowg + row2)*512 + ch*16 + c4),
            v, __ATOMIC_RELAXED, __HIP_MEMORY_SCOPE_AGENT);
        __atomic_signal_fence(__ATOMIC_SEQ_CST);
        __builtin_amdgcn_s_waitcnt(0);   // h stores complete at coherence point
        __atomic_signal_fence(__ATOMIC_SEQ_CST);
        if (ln == 0)
          __hip_atomic_store(tag + ((bt<<5) + ch)*16, (unsigned)(t+1),
                             __ATOMIC_RELAXED, __HIP_MEMORY_SCOPE_AGENT);
      }
    }
  }

  // ---- loss reduction (chunk-0 blocks only) ----
  if (ch == 0) {
    red[tid] = loss_acc;
    __syncthreads();
    if (tid == 0) {
      float s = 0.f;
      for (int i=0;i<256;i++) s += red[i];
      atomicAdd(out, 0.3f * s);
    }
  }
}

// ---------------- launch ----------------

extern "C" void kernel_launch(void* const* d_in, const int* in_sizes, int n_in,
                              void* d_out, int out_size, void* d_ws, size_t ws_size,
                              hipStream_t stream) {
  const float* data = (const float*)d_in[0];
  const float* W_ih = (const float*)d_in[1];
  const float* b_ih = (const float*)d_in[2];
  const float* W_hh = (const float*)d_in[3];
  const float* b_hh = (const float*)d_in[4];
  const float* Wdh  = (const float*)d_in[5];
  const float* bdh  = (const float*)d_in[6];
  // d_in[7] Wdx, d_in[8] bdx: dead code in reference forward
  const float* Wh   = (const float*)d_in[9];
  const float* bh   = (const float*)d_in[10];
  const float* Wf   = (const float*)d_in[11];
  const float* bf   = (const float*)d_in[12];
  // d_in[13] Wc, d_in[14] bc: dead code
  float* out = (float*)d_out;
  unsigned char* ws = (unsigned char*)d_ws;

  k_zero     <<<273,  256, 0, stream>>>((unsigned int*)d_ws, out);
  k_mask     <<<16384,256, 0, stream>>>(data, (float*)(ws + OFF_MSUM));
  k_delta    <<<512,  64,  0, stream>>>(data, (_Float16*)(ws + OFF_DBF));
  k_pack_wh  <<<256,  256, 0, stream>>>(Wh,  (_Float16*)(ws + OFF_WH));
  k_pack_wf  <<<64,   256, 0, stream>>>(Wf,  (_Float16*)(ws + OFF_WF));
  k_pack_wd  <<<256,  256, 0, stream>>>(Wdh, (_Float16*)(ws + OFF_WD));
  k_pack_gb  <<<6144, 256, 0, stream>>>(W_ih, W_hh, (_Float16*)(ws + OFF_GB));
  k_pack_bias<<<8,    256, 0, stream>>>(b_ih, b_hh, (float*)(ws + OFF_BG));
  brits_main <<<256,  256, 0, stream>>>(data, bh, bf, bdh, ws, out);
}

// Round 7
// 1659.851 us; speedup vs baseline: 1.4140x; 1.4140x over previous
//
#include <hip/hip_runtime.h>

// BRITS-style recurrent imputation on MI355X.
// 8 batch-tiles(16 rows) x 32 H-chunks = 256 blocks; bt = blockIdx&7 so a
// tile's 32 blocks share one XCD under round-robin dispatch.
// R7: builtin-only XCD-local exchange. Producers: plain cached stores (land in
// own-XCD L2). Consumers: global_load_lds with aux=1 (sc0: bypass L1, read L2)
// into LDS. hbuf stored in MFMA-fragment order (lane-linear staging + reads).
// One-time double-sentinel handshake validates the transport per tile; tiles
// that fail it use the R4-proven agent-UC path. No inline asm instructions.

#define B_ 128
#define T_ 256
#define D_ 128
#define H_ 512

typedef _Float16 f16x8 __attribute__((ext_vector_type(8)));
typedef float    f32x4 __attribute__((ext_vector_type(4)));

#define AS1 __attribute__((address_space(1)))
#define AS3 __attribute__((address_space(3)))

// ---- workspace layout (bytes), total 12,149,760 (< R1-proven 20,497,408) ----
#define OFF_HBUF   0u          // f16 [2][8 tiles][16KB frag-order]  262144
#define OFF_TAG    262144u     // uint [8][32] @64B        16384
#define OFF_DFLG   278528u     // uint [8][32] @64B        16384 (UC handshake flags)
#define OFF_DSNT   294912u     // uint [8][32] @64B        16384 (plain-store sentinels)
#define OFF_MSUM   311296u     // float [256]              1024
#define OFF_BG     312320u     // float [2048]             8192
#define OFF_WH     320512u     // f16 [8][16][64][8]       131072
#define OFF_WF     451584u     // f16 [8][4][64][8]        32768
#define OFF_WD     484352u     // f16 [32][4][64][8]       131072
#define OFF_GB     615424u     // f16 [32][4][24][64][8]   3145728
#define OFF_DBF    3761152u    // f16 [128][256][128]      8388608

__device__ __forceinline__ float sigm(float x)  { return __fdividef(1.0f, 1.0f + __expf(-x)); }
__device__ __forceinline__ float tanh_(float x) { return 1.0f - __fdividef(2.0f, __expf(2.0f*x) + 1.0f); }

// ---------------- pre-kernels ----------------

__global__ void k_zero(unsigned int* __restrict__ wsu, float* __restrict__ out){
  int id = blockIdx.x*256 + threadIdx.x;
  if (id < 78080) wsu[id] = 0u;     // hbuf + tag + dflg + dsnt + msum
  if (id == 0) out[0] = 0.0f;
}

__global__ void k_mask(const float* __restrict__ data, float* __restrict__ msum){
  int idx = blockIdx.x*256 + threadIdx.x;     // < 128*256*128
  float v = data[idx];
  bool m = (v == v);
  unsigned long long bal = __ballot(m);
  if ((threadIdx.x & 63) == 0) {
    int t = (idx >> 7) & 255;
    atomicAdd(&msum[t], (float)__popcll(bal));
  }
}

// delta_calc, wave-cooperative (exact reference semantics)
__global__ void k_delta(const float* __restrict__ data, _Float16* __restrict__ dbf){
  int b  = blockIdx.x >> 2;
  int t0 = (blockIdx.x & 3) * 64;
  int ln = threadIdx.x;                       // 0..63
  __shared__ unsigned long long rm[65][2];
  for (int r = 0; r < 65; ++r) {
    int t = t0 - 1 + r;
    unsigned long long m0 = 0, m1 = 0;
    if (t >= 0) {
      const float* row = data + ((size_t)b*256 + t)*128;
      float a = row[ln], c = row[64 + ln];
      m0 = __ballot(a == a);
      m1 = __ballot(c == c);
    }
    if (ln == 0) { rm[r][0] = m0; rm[r][1] = m1; }
  }
  __syncthreads();
  int t = t0 + ln;
  _Float16* orow = dbf + ((size_t)b*256 + t)*128;
  if (t == 0) {
    f16x8 z;
    #pragma unroll
    for (int i=0;i<8;i++) z[i] = (_Float16)0.0f;
    #pragma unroll
    for (int k=0;k<16;k++) ((f16x8*)orow)[k] = z;
    return;
  }
  unsigned long long mp0 = rm[ln][0],   mp1 = rm[ln][1];
  unsigned long long mt0 = rm[ln+1][0], mt1 = rm[ln+1][1];
  float carry = 0.0f;
  for (int g = 0; g < 16; ++g) {
    f16x8 v;
    #pragma unroll
    for (int j = 0; j < 8; ++j) {
      int d = g*8 + j;
      bool prevm = (d < 64)   ? ((mp0 >> d) & 1ull)        : ((mp1 >> (d-64)) & 1ull);
      int dm1 = (d - 1) & 127;
      bool leftm = (dm1 < 64) ? ((mt0 >> dm1) & 1ull)      : ((mt1 >> (dm1-64)) & 1ull);
      float val = (!prevm) ? (carry + 1.0f) : (leftm ? 1.0f : 0.0f);
      carry = val;
      v[j] = (_Float16)val;
    }
    ((f16x8*)orow)[g] = v;
  }
}

// Weight pre-pack into MFMA B-fragment order: [..][ks][lane][8], B[k][n]=W[n][k],
// n = lane&15, k = ks*32 + (lane>>4)*8 + j.
__global__ void k_pack_wh(const float* __restrict__ Wh, _Float16* __restrict__ dst){
  int id = blockIdx.x*256 + threadIdx.x;      // 65536 = [8][16][64][8]
  int j = id & 7, l = (id>>3)&63, ks = (id>>9)&15, nt = id>>13;
  int row = nt*16 + (l&15);
  int k   = ks*32 + ((l>>4)&3)*8 + j;
  dst[id] = (_Float16)Wh[row*512 + k];
}
__global__ void k_pack_wf(const float* __restrict__ Wf, _Float16* __restrict__ dst){
  int id = blockIdx.x*256 + threadIdx.x;      // 16384 = [8][4][64][8]
  int j = id & 7, l = (id>>3)&63, ks = (id>>9)&3, nt = id>>11;
  int row = nt*16 + (l&15);
  int k   = ks*32 + ((l>>4)&3)*8 + j;
  float v = (row == k) ? 0.0f : Wf[row*128 + k];   // off-diagonal mask
  dst[id] = (_Float16)v;
}
__global__ void k_pack_wd(const float* __restrict__ Wdh, _Float16* __restrict__ dst){
  int id = blockIdx.x*256 + threadIdx.x;      // 65536 = [32][4][64][8]
  int j = id & 7, l = (id>>3)&63, ks = (id>>9)&3, c = id>>11;
  int row = c*16 + (l&15);
  int k   = ks*32 + ((l>>4)&3)*8 + j;
  dst[id] = (_Float16)Wdh[row*128 + k];
}
__global__ void k_pack_gb(const float* __restrict__ W_ih, const float* __restrict__ W_hh,
                          _Float16* __restrict__ dst){
  int id = blockIdx.x*256 + threadIdx.x;      // 1572864 = [32][4][24][64][8]
  int j = id & 7, l = (id>>3)&63;
  int f = id>>9;
  int ks = f % 24; f /= 24;
  int g = f & 3, c = f >> 2;
  int rn = g*512 + c*16 + (l&15);
  int k  = ks*32 + ((l>>4)&3)*8 + j;          // inp K: [0,256)=[c_c,m], [256,768)=h
  float v = (k < 256) ? W_ih[rn*256 + k] : W_hh[rn*512 + (k-256)];
  dst[id] = (_Float16)v;
}
__global__ void k_pack_bias(const float* __restrict__ b_ih, const float* __restrict__ b_hh,
                            float* __restrict__ dst){
  int id = blockIdx.x*256 + threadIdx.x;      // 2048
  dst[id] = b_ih[id] + b_hh[id];
}

// ---------------- main persistent kernel ----------------

__global__ __launch_bounds__(256, 1) void brits_main(
    const float* __restrict__ data,
    const float* __restrict__ bh,
    const float* __restrict__ bfv,
    const float* __restrict__ bdh,
    unsigned char* __restrict__ ws,
    float* __restrict__ out)
{
  const int bt  = blockIdx.x & 7;     // batch tile (== XCD under round-robin)
  const int ch  = blockIdx.x >> 3;    // H chunk 0..31
  const int tid = threadIdx.x;
  const int wv  = tid >> 6;           // wave 0..3
  const int ln  = tid & 63;
  const int l15 = ln & 15;
  const int lq  = ln >> 4;

  _Float16*       hbuf = (_Float16*)(ws + OFF_HBUF);
  unsigned int*   tag  = (unsigned int*)(ws + OFF_TAG);
  unsigned int*   dflg = (unsigned int*)(ws + OFF_DFLG);
  unsigned int*   dsnt = (unsigned int*)(ws + OFF_DSNT);
  const float*    msum = (const float*)(ws + OFF_MSUM);
  const float*    bgq  = (const float*)(ws + OFF_BG);
  const f16x8*    WhP  = (const f16x8*)(ws + OFF_WH);
  const f16x8*    WfP  = (const f16x8*)(ws + OFF_WF);
  const f16x8*    WdP  = (const f16x8*)(ws + OFF_WD);
  const f16x8*    GBP  = (const f16x8*)(ws + OFF_GB);
  const _Float16* dbf  = (const _Float16*)(ws + OFF_DBF);

  __shared__ __align__(16) _Float16 xcT[16][136];
  __shared__ __align__(16) _Float16 ccT[16][136];
  __shared__ __align__(8)  _Float16 hstg[16][16];
  __shared__ __align__(16) _Float16 hstage[8192];    // 16KB fragment-order h
  __shared__ unsigned int sbounce[4][64];            // GLC bounce slices
  __shared__ float gbuf[4][16][16];
  __shared__ float cst[16][16];
  __shared__ float invms[256];
  __shared__ float bh_s[128], bf_s[128], bdh_s[16], bg_s[4][16];
  __shared__ float red[256];
  __shared__ int wres[4], wres2[4];

  // ---------- one-time transport validation (double sentinel) ----------
  unsigned int* myflg = dflg + ((bt<<5) + ch)*16;
  unsigned int* mysnt = dsnt + ((bt<<5) + ch)*16;
  const unsigned int* pollflg = dflg + ((bt<<5) + (ln & 31))*16;

  auto poll_uc = [&](unsigned thr){
    for (;;) {
      bool ok = true;
      if (ln < 32)
        ok = (__hip_atomic_load(pollflg, __ATOMIC_RELAXED,
                                __HIP_MEMORY_SCOPE_AGENT) & 15u) >= thr;
      if (__ballot(ok) == ~0ull) break;
      __builtin_amdgcn_s_sleep(8);
    }
  };
  auto bounce_check = [&](unsigned base)->bool{
    if (ln < 32)
      __builtin_amdgcn_global_load_lds(
          (const AS1 void*)(dsnt + ((bt<<5) + (ln & 31))*16),
          (AS3 void*)&sbounce[wv][0], 4, 0, 1 /*sc0*/);
    __asm__ __volatile__("" ::: "memory");
    __builtin_amdgcn_s_waitcnt(0);
    __asm__ __volatile__("" ::: "memory");
    bool ok = true;
    if (ln < 32) ok = (sbounce[wv][ln] == (base | (unsigned)(bt<<8) | (unsigned)(ln & 31)));
    return __ballot(ok) == ~0ull;
  };

  if (tid == 0) {
    mysnt[0] = 0xA5000000u | (bt<<8) | ch;          // plain cached store
    __asm__ __volatile__("" ::: "memory");
    __builtin_amdgcn_s_waitcnt(0);
    __hip_atomic_store(myflg, 1u, __ATOMIC_RELAXED, __HIP_MEMORY_SCOPE_AGENT);
  }
  poll_uc(1);
  { bool o = bounce_check(0xA5000000u); if (ln == 0) wres[wv] = o ? 1 : 0; }
  __syncthreads();
  if (tid == 0)
    __hip_atomic_store(myflg, 2u, __ATOMIC_RELAXED, __HIP_MEMORY_SCOPE_AGENT);
  poll_uc(2);                                        // all blocks done phase-1 reads
  if (tid == 0) {
    mysnt[0] = 0x5A000000u | (bt<<8) | ch;          // overwrite same address
    __asm__ __volatile__("" ::: "memory");
    __builtin_amdgcn_s_waitcnt(0);
    __hip_atomic_store(myflg, 3u, __ATOMIC_RELAXED, __HIP_MEMORY_SCOPE_AGENT);
  }
  poll_uc(3);
  { bool o = bounce_check(0x5A000000u); if (ln == 0) wres2[wv] = o ? 1 : 0; }
  __syncthreads();
  if (tid == 0) {
    int bok = wres[0]&wres[1]&wres[2]&wres[3]&wres2[0]&wres2[1]&wres2[2]&wres2[3];
    __hip_atomic_store(myflg, 4u | (bok ? 16u : 0u),
                       __ATOMIC_RELAXED, __HIP_MEMORY_SCOPE_AGENT);
  }
  bool fast;
  {
    unsigned v = 0;
    for (;;) {
      bool ok = true;
      if (ln < 32) {
        v = __hip_atomic_load(pollflg, __ATOMIC_RELAXED, __HIP_MEMORY_SCOPE_AGENT);
        ok = (v & 15u) >= 4u;
      }
      if (__ballot(ok) == ~0ull) break;
      __builtin_amdgcn_s_sleep(8);
    }
    fast = (__ballot((ln >= 32) || (v & 16u)) == ~0ull);
  }

  invms[tid] = 1.0f / (msum[tid] + 1e-5f);
  if (tid < 128) { bh_s[tid] = bh[tid]; bf_s[tid] = bfv[tid]; }
  if (tid < 16)  bdh_s[tid] = bdh[ch*16 + tid];
  if (tid < 64)  bg_s[tid>>4][tid&15] = bgq[(tid>>4)*512 + ch*16 + (tid&15)];
  ((float*)cst)[tid] = 0.0f;
  __syncthreads();

  // ---- persistent weight fragments in VGPRs ----
  f16x8 WhB[2][16], WfB[2][4], GB[24], WdB[4];
  #pragma unroll
  for (int i=0;i<2;i++)
    #pragma unroll
    for (int ks=0;ks<16;ks++)
      WhB[i][ks] = WhP[((2*wv+i)*16 + ks)*64 + ln];
  #pragma unroll
  for (int i=0;i<2;i++)
    #pragma unroll
    for (int ks=0;ks<4;ks++)
      WfB[i][ks] = WfP[((2*wv+i)*4 + ks)*64 + ln];
  #pragma unroll
  for (int ks=0;ks<24;ks++)
    GB[ks] = GBP[((ch*4 + wv)*24 + ks)*64 + ln];
  #pragma unroll
  for (int ks=0;ks<4;ks++)
    WdB[ks] = WdP[(ch*4 + ks)*64 + ln];

  float loss_acc = 0.0f;
  const int rowg = bt*16;

  // producer store address (fragment-order layout), 8B = 4 cols of one row
  const int prow = ln >> 2;
  const int pc0  = ch*16 + (ln & 3)*4;
  const size_t pelem = ((size_t)((pc0 >> 5)*64 + ((pc0 >> 3) & 3)*16 + prow))*8 + (pc0 & 7);
  unsigned int* tagw = tag + ((bt<<5) + ch)*16;
  const unsigned int* tagslot = tag + ((bt<<5) + (ln & 31))*16;

  #pragma unroll 1
  for (int t = 0; t < 256; ++t) {
    // ---- prefetch everything that doesn't depend on h(t) ----
    float xnv[2][4], mmv[2][4];
    #pragma unroll
    for (int i=0;i<2;i++){
      int col = (2*wv+i)*16 + l15;
      #pragma unroll
      for (int r=0;r<4;r++){
        float dv = data[((rowg + lq*4 + r)*256 + t)*128 + col];
        bool ok = (dv == dv);
        xnv[i][r] = ok ? dv : 0.0f;
        mmv[i][r] = ok ? 1.0f : 0.0f;
      }
    }
    f16x8 mA[4];
    {
      const float* mrow = data + ((size_t)(rowg + l15)*256 + t)*128 + lq*8;
      #pragma unroll
      for (int k=0;k<4;k++){
        float4 a0 = *(const float4*)(mrow + k*32);
        float4 a1 = *(const float4*)(mrow + k*32 + 4);
        f16x8 mv;
        mv[0] = (a0.x==a0.x)?(_Float16)1.0f:(_Float16)0.0f;
        mv[1] = (a0.y==a0.y)?(_Float16)1.0f:(_Float16)0.0f;
        mv[2] = (a0.z==a0.z)?(_Float16)1.0f:(_Float16)0.0f;
        mv[3] = (a0.w==a0.w)?(_Float16)1.0f:(_Float16)0.0f;
        mv[4] = (a1.x==a1.x)?(_Float16)1.0f:(_Float16)0.0f;
        mv[5] = (a1.y==a1.y)?(_Float16)1.0f:(_Float16)0.0f;
        mv[6] = (a1.z==a1.z)?(_Float16)1.0f:(_Float16)0.0f;
        mv[7] = (a1.w==a1.w)?(_Float16)1.0f:(_Float16)0.0f;
        mA[k] = mv;
      }
    }
    // gamma_h(t+1) pre-activation: h-independent, hoisted into the wait window
    f32x4 ga = {0.f,0.f,0.f,0.f};
    if (wv == 0 && t < 255) {
      f16x8 dA[4];
      #pragma unroll
      for (int k=0;k<4;k++)
        dA[k] = *(const f16x8*)(dbf + ((size_t)(rowg+l15)*256 + (t+1))*128 + k*32 + lq*8);
      #pragma unroll
      for (int k=0;k<4;k++)
        ga = __builtin_amdgcn_mfma_f32_16x16x32_f16(dA[k], WdB[k], ga, 0,0,0);
    }

    // ---- wait for h(t) ----
    if (t > 0) {
      if (fast) {
        for (;;) {
          if (ln < 32)
            __builtin_amdgcn_global_load_lds((const AS1 void*)tagslot,
                (AS3 void*)&sbounce[wv][0], 4, 0, 1 /*sc0*/);
          __asm__ __volatile__("" ::: "memory");
          __builtin_amdgcn_s_waitcnt(0);
          __asm__ __volatile__("" ::: "memory");
          bool ok = true;
          if (ln < 32) ok = sbounce[wv][ln] >= (unsigned)t;
          if (__ballot(ok) == ~0ull) break;
          __builtin_amdgcn_s_sleep(1);
        }
      } else {
        for (;;) {
          bool ok = true;
          if (ln < 32)
            ok = __hip_atomic_load(tagslot, __ATOMIC_RELAXED,
                                   __HIP_MEMORY_SCOPE_AGENT) >= (unsigned)t;
          if (__ballot(ok) == ~0ull) break;
          __builtin_amdgcn_s_sleep(1);
        }
      }
    }

    // ---- h A-fragments ----
    f16x8 hA[16];
    const char* hbB = (const char*)hbuf + (size_t)(((t&1)*8 + bt))*16384;
    if (fast) {
      // cooperative lane-linear staging of the 16KB fragment-order h block
      #pragma unroll
      for (int s=0;s<4;s++){
        int off = s*4096 + wv*1024;
        __builtin_amdgcn_global_load_lds((const AS1 void*)(hbB + off + ln*16),
            (AS3 void*)((char*)hstage + off), 16, 0, 1 /*sc0*/);
      }
      __asm__ __volatile__("" ::: "memory");
      __builtin_amdgcn_s_waitcnt(0);
      __syncthreads();
      #pragma unroll
      for (int ks=0;ks<16;ks++)
        hA[ks] = *(const f16x8*)((const char*)hstage + ks*1024 + ln*16);
    } else {
      #pragma unroll
      for (int ks=0;ks<16;ks++) {
        const char* p = hbB + (size_t)(ks*64 + ln)*16;
        union { unsigned long long u[2]; f16x8 v; } cv;
        cv.u[0] = __hip_atomic_load((const unsigned long long*)p,
                                    __ATOMIC_RELAXED, __HIP_MEMORY_SCOPE_AGENT);
        cv.u[1] = __hip_atomic_load((const unsigned long long*)(p + 8),
                                    __ATOMIC_RELAXED, __HIP_MEMORY_SCOPE_AGENT);
        hA[ks] = cv.v;
      }
    }

    // ---- x_h = sigmoid(h @ Wh^T + bh); loss1; x_c ----
    float xhv[2][4];
    float numer = 0.0f;
    #pragma unroll
    for (int i=0;i<2;i++){
      f32x4 a0 = {0.f,0.f,0.f,0.f}, a1 = {0.f,0.f,0.f,0.f};
      #pragma unroll
      for (int ks=0;ks<8;ks++){
        a0 = __builtin_amdgcn_mfma_f32_16x16x32_f16(hA[ks],   WhB[i][ks],   a0, 0,0,0);
        a1 = __builtin_amdgcn_mfma_f32_16x16x32_f16(hA[ks+8], WhB[i][ks+8], a1, 0,0,0);
      }
      int col = (2*wv+i)*16 + l15;
      float bhc = bh_s[col];
      #pragma unroll
      for (int r=0;r<4;r++){
        float s = sigm(a0[r] + a1[r] + bhc);
        xhv[i][r] = s;
        numer += fabsf(xnv[i][r] - s) * mmv[i][r];
        float xc = (mmv[i][r] > 0.f) ? xnv[i][r] : s;
        xcT[lq*4 + r][col] = (_Float16)xc;
      }
    }
    __syncthreads();

    // ---- z_h MFMAs + gate partials (h & m parts) interleaved ----
    f16x8 xcA[4];
    #pragma unroll
    for (int k=0;k<4;k++)
      xcA[k] = *(const f16x8*)(&xcT[l15][k*32 + lq*8]);
    f32x4 z0 = {0.f,0.f,0.f,0.f}, z1 = {0.f,0.f,0.f,0.f};
    #pragma unroll
    for (int ks=0;ks<4;ks++){
      z0 = __builtin_amdgcn_mfma_f32_16x16x32_f16(xcA[ks], WfB[0][ks], z0, 0,0,0);
      z1 = __builtin_amdgcn_mfma_f32_16x16x32_f16(xcA[ks], WfB[1][ks], z1, 0,0,0);
    }
    f32x4 g0 = {0.f,0.f,0.f,0.f}, g1 = {0.f,0.f,0.f,0.f};
    #pragma unroll
    for (int k=0;k<4;k++){
      g0 = __builtin_amdgcn_mfma_f32_16x16x32_f16(mA[k],   GB[4+k],  g0, 0,0,0);
      g1 = __builtin_amdgcn_mfma_f32_16x16x32_f16(hA[k+8], GB[16+k], g1, 0,0,0);
    }
    #pragma unroll
    for (int ks=0;ks<8;ks++)
      g0 = __builtin_amdgcn_mfma_f32_16x16x32_f16(hA[ks], GB[8+ks], g0, 0,0,0);
    #pragma unroll
    for (int ks=4;ks<8;ks++)
      g1 = __builtin_amdgcn_mfma_f32_16x16x32_f16(hA[ks+8], GB[16+ks], g1, 0,0,0);

    // ---- z_h epilogue: loss2, c_c, distributed imputation store ----
    #pragma unroll
    for (int i=0;i<2;i++){
      f32x4 a = (i==0) ? z0 : z1;
      int col = (2*wv+i)*16 + l15;
      float bfc = bf_s[col];
      bool mine = ((col >> 2) == ch);
      #pragma unroll
      for (int r=0;r<4;r++){
        float z = sigm(a[r] + bfc);
        numer += fabsf(xnv[i][r] - z) * mmv[i][r];
        float chv = fabsf(0.5f*z + 0.5f*xhv[i][r]);
        float cc  = (mmv[i][r] > 0.f) ? xnv[i][r] : chv;
        int row = lq*4 + r;
        ccT[row][col] = (_Float16)cc;
        if (mine) out[1 + ((size_t)(rowg+row)*256 + t)*128 + col] = cc;
      }
    }
    if (ch == 0) loss_acc += numer * invms[t];
    __syncthreads();

    // ---- gates: add c_c part, reduce, stash ----
    f16x8 ccA[4];
    #pragma unroll
    for (int k=0;k<4;k++)
      ccA[k] = *(const f16x8*)(&ccT[l15][k*32 + lq*8]);
    #pragma unroll
    for (int k=0;k<4;k++)
      g0 = __builtin_amdgcn_mfma_f32_16x16x32_f16(ccA[k], GB[k], g0, 0,0,0);
    #pragma unroll
    for (int r=0;r<4;r++) gbuf[wv][lq*4 + r][l15] = g0[r] + g1[r];
    __syncthreads();

    // ---- LSTM cell epilogue + gamma_h(t+1)-scaled h store + tag (wave 0) ----
    if (wv == 0) {
      #pragma unroll
      for (int r=0;r<4;r++){
        int row = lq*4 + r;
        float ii = gbuf[0][row][l15] + bg_s[0][l15];
        float ff = gbuf[1][row][l15] + bg_s[1][l15];
        float gg = gbuf[2][row][l15] + bg_s[2][l15];
        float oo = gbuf[3][row][l15] + bg_s[3][l15];
        float co = cst[row][l15];
        float cn = sigm(ff)*co + sigm(ii)*tanh_(gg);
        cst[row][l15] = cn;
        if (t < 255) {
          float hn = sigm(oo)*tanh_(cn);
          float gh = __expf(-fmaxf(ga[r] + bdh_s[l15], 0.0f));
          hstg[row][l15] = (_Float16)(hn * gh);
        }
      }
      if (t < 255) {
        __asm__ __volatile__("" ::: "memory");
        unsigned long long v = *(const unsigned long long*)&hstg[prow][(ln & 3)*4];
        char* dp = (char*)hbuf + (size_t)((((t+1)&1)*8 + bt))*16384 + pelem*2;
        unsigned tv = (unsigned)(t+1);
        if (fast) {
          *(unsigned long long*)dp = v;                 // plain store -> own-XCD L2
          __asm__ __volatile__("" ::: "memory");
          __builtin_amdgcn_s_waitcnt(0);                // h in L2 before tag
          __asm__ __volatile__("" ::: "memory");
          if (ln == 0) tagw[0] = tv;                    // plain tag store
          __asm__ __volatile__("" ::: "memory");
        } else {
          __hip_atomic_store((unsigned long long*)dp, v,
                             __ATOMIC_RELAXED, __HIP_MEMORY_SCOPE_AGENT);
          __atomic_signal_fence(__ATOMIC_SEQ_CST);
          __builtin_amdgcn_s_waitcnt(0);
          __atomic_signal_fence(__ATOMIC_SEQ_CST);
          if (ln == 0)
            __hip_atomic_store(tagw, tv,
                               __ATOMIC_RELAXED, __HIP_MEMORY_SCOPE_AGENT);
        }
      }
    }
  }

  // ---- loss reduction (chunk-0 blocks only) ----
  if (ch == 0) {
    red[tid] = loss_acc;
    __syncthreads();
    if (tid == 0) {
      float s = 0.f;
      for (int i=0;i<256;i++) s += red[i];
      atomicAdd(out, 0.3f * s);
    }
  }
}

// ---------------- launch ----------------

extern "C" void kernel_launch(void* const* d_in, const int* in_sizes, int n_in,
                              void* d_out, int out_size, void* d_ws, size_t ws_size,
                              hipStream_t stream) {
  const float* data = (const float*)d_in[0];
  const float* W_ih = (const float*)d_in[1];
  const float* b_ih = (const float*)d_in[2];
  const float* W_hh = (const float*)d_in[3];
  const float* b_hh = (const float*)d_in[4];
  const float* Wdh  = (const float*)d_in[5];
  const float* bdh  = (const float*)d_in[6];
  // d_in[7] Wdx, d_in[8] bdx: dead code in reference forward
  const float* Wh   = (const float*)d_in[9];
  const float* bh   = (const float*)d_in[10];
  const float* Wf   = (const float*)d_in[11];
  const float* bf   = (const float*)d_in[12];
  // d_in[13] Wc, d_in[14] bc: dead code
  float* out = (float*)d_out;
  unsigned char* ws = (unsigned char*)d_ws;

  k_zero     <<<305,  256, 0, stream>>>((unsigned int*)d_ws, out);
  k_mask     <<<16384,256, 0, stream>>>(data, (float*)(ws + OFF_MSUM));
  k_delta    <<<512,  64,  0, stream>>>(data, (_Float16*)(ws + OFF_DBF));
  k_pack_wh  <<<256,  256, 0, stream>>>(Wh,  (_Float16*)(ws + OFF_WH));
  k_pack_wf  <<<64,   256, 0, stream>>>(Wf,  (_Float16*)(ws + OFF_WF));
  k_pack_wd  <<<256,  256, 0, stream>>>(Wdh, (_Float16*)(ws + OFF_WD));
  k_pack_gb  <<<6144, 256, 0, stream>>>(W_ih, W_hh, (_Float16*)(ws + OFF_GB));
  k_pack_bias<<<8,    256, 0, stream>>>(b_ih, b_hh, (float*)(ws + OFF_BG));
  brits_main <<<256,  256, 0, stream>>>(data, bh, bf, bdh, ws, out);
}

// Round 8
// 1283.793 us; speedup vs baseline: 1.8282x; 1.2929x over previous
//
#include <hip/hip_runtime.h>

// BRITS-style recurrent imputation on MI355X.
// 8 batch-tiles(16 rows) x 32 H-chunks = 256 blocks; bt = blockIdx&7 so a
// tile's 32 blocks share one XCD under round-robin dispatch.
// R8: 3-tier validated transport. tier0 = nt loads (L1 no-allocate) straight
//     to VGPRs (no LDS bounce/stage/barrier); tier1 = R7 sc0 global_load_lds
//     bounce; tier2 = agent-UC (R4-proven). Double-sentinel (same-address
//     reread after remote overwrite) validates each tier per tile at runtime.
//     Out-stores moved post-barrier (wave1, from fp32 ccF LDS) so no barrier
//     or producer path drains HBM stores. gbuf/cst padded (4-way conflicts).
//     All pre-kernels fused into one k_prep launch (msum via popcount).

#define B_ 128
#define T_ 256
#define D_ 128
#define H_ 512

typedef _Float16 f16x8 __attribute__((ext_vector_type(8)));
typedef float    f32x4 __attribute__((ext_vector_type(4)));
typedef unsigned int u32x4 __attribute__((ext_vector_type(4)));

#define AS1 __attribute__((address_space(1)))
#define AS3 __attribute__((address_space(3)))

// ---- workspace layout (bytes), total 12,166,144 (< R1-proven 20,497,408) ----
#define OFF_HBUF   0u          // f16 [2][8 tiles][16KB frag-order]  262144
#define OFF_TAG    262144u     // uint [8][32] @64B        16384
#define OFF_DFLG   278528u     // uint [8][32] @64B        16384 (UC handshake flags)
#define OFF_DSNT   294912u     // uint [8][32] @64B        16384 (bounce-test sentinels)
#define OFF_DSN2   311296u     // uint [8][32] @64B        16384 (nt-test sentinels)
#define OFF_MSUM   327680u     // float [256]              1024
#define OFF_BG     328704u     // float [2048]             8192
#define OFF_WH     336896u     // f16 [8][16][64][8]       131072
#define OFF_WF     467968u     // f16 [8][4][64][8]        32768
#define OFF_WD     500736u     // f16 [32][4][64][8]       131072
#define OFF_GB     631808u     // f16 [32][4][24][64][8]   3145728
#define OFF_DBF    3777536u    // f16 [128][256][128]      8388608

__device__ __forceinline__ float sigm(float x)  { return __fdividef(1.0f, 1.0f + __expf(-x)); }
__device__ __forceinline__ float tanh_(float x) { return 1.0f - __fdividef(2.0f, __expf(2.0f*x) + 1.0f); }

// ---------------- fused pre-kernel ----------------
// blocks [0,320) zero ws control regions + out[0]
//        [320,576) msum per t (popcount, no atomics)
//        [576,704) delta (4 wave-units per block)
//        [704,960) pack Wh | [960,1024) pack Wf | [1024,1280) pack Wdh
//        [1280,7424) pack gates | [7424,7432) pack bias
__global__ void k_prep(const float* __restrict__ data,
                       const float* __restrict__ W_ih, const float* __restrict__ W_hh,
                       const float* __restrict__ Wdh,  const float* __restrict__ Wh,
                       const float* __restrict__ Wf,
                       const float* __restrict__ b_ih, const float* __restrict__ b_hh,
                       unsigned char* __restrict__ ws, float* __restrict__ out)
{
  const int blk = blockIdx.x, tid = threadIdx.x;
  if (blk < 320) {
    ((unsigned int*)ws)[blk*256 + tid] = 0u;    // hbuf+tag+dflg+dsnt+dsn2 = 81920 words
    if (blk == 0 && tid == 0) out[0] = 0.0f;
    return;
  }
  if (blk < 576) {                              // msum[t]
    int t = blk - 320;
    int cnt = 0;
    for (int i = 0; i < 64; ++i) {
      int e = tid + 256*i;                      // 0..16383
      int b = e >> 7, d = e & 127;
      float v = data[((size_t)(b*256) + t)*128 + d];
      cnt += (v == v) ? 1 : 0;
    }
    __shared__ int ism[256];
    ism[tid] = cnt;
    __syncthreads();
    if (tid == 0) {
      int s = 0;
      for (int i = 0; i < 256; ++i) s += ism[i];
      ((float*)(ws + OFF_MSUM))[t] = (float)s;
    }
    return;
  }
  if (blk < 704) {                              // delta: one 64-lane wave per (b, t-quarter)
    _Float16* dbf = (_Float16*)(ws + OFF_DBF);
    int wv = tid >> 6, ln = tid & 63;
    int unit = (blk - 576)*4 + wv;              // 0..511
    int b  = unit >> 2;
    int t0 = (unit & 3) * 64;
    __shared__ unsigned long long rm[4][65][2];
    for (int r = 0; r < 65; ++r) {
      int t = t0 - 1 + r;
      unsigned long long m0 = 0, m1 = 0;
      if (t >= 0) {
        const float* row = data + ((size_t)b*256 + t)*128;
        float a = row[ln], c = row[64 + ln];
        m0 = __ballot(a == a);
        m1 = __ballot(c == c);
      }
      if (ln == 0) { rm[wv][r][0] = m0; rm[wv][r][1] = m1; }
    }
    // intra-wave LDS RAW is ordered (compiler lgkmcnt); no cross-wave sharing
    int t = t0 + ln;
    _Float16* orow = dbf + ((size_t)b*256 + t)*128;
    if (t == 0) {
      f16x8 z;
      #pragma unroll
      for (int i=0;i<8;i++) z[i] = (_Float16)0.0f;
      #pragma unroll
      for (int k=0;k<16;k++) ((f16x8*)orow)[k] = z;
      return;
    }
    unsigned long long mp0 = rm[wv][ln][0],   mp1 = rm[wv][ln][1];
    unsigned long long mt0 = rm[wv][ln+1][0], mt1 = rm[wv][ln+1][1];
    float carry = 0.0f;
    for (int g = 0; g < 16; ++g) {
      f16x8 v;
      #pragma unroll
      for (int j = 0; j < 8; ++j) {
        int d = g*8 + j;
        bool prevm = (d < 64)   ? ((mp0 >> d) & 1ull)   : ((mp1 >> (d-64)) & 1ull);
        int dm1 = (d - 1) & 127;
        bool leftm = (dm1 < 64) ? ((mt0 >> dm1) & 1ull) : ((mt1 >> (dm1-64)) & 1ull);
        float val = (!prevm) ? (carry + 1.0f) : (leftm ? 1.0f : 0.0f);
        carry = val;
        v[j] = (_Float16)val;
      }
      ((f16x8*)orow)[g] = v;
    }
    return;
  }
  if (blk < 960) {                              // pack Wh -> B-frag
    int id = (blk - 704)*256 + tid;             // [8][16][64][8]
    int j = id & 7, l = (id>>3)&63, ks = (id>>9)&15, nt = id>>13;
    int row = nt*16 + (l&15);
    int k   = ks*32 + ((l>>4)&3)*8 + j;
    ((_Float16*)(ws + OFF_WH))[id] = (_Float16)Wh[row*512 + k];
    return;
  }
  if (blk < 1024) {                             // pack Wf (off-diag masked)
    int id = (blk - 960)*256 + tid;             // [8][4][64][8]
    int j = id & 7, l = (id>>3)&63, ks = (id>>9)&3, nt = id>>11;
    int row = nt*16 + (l&15);
    int k   = ks*32 + ((l>>4)&3)*8 + j;
    float v = (row == k) ? 0.0f : Wf[row*128 + k];
    ((_Float16*)(ws + OFF_WF))[id] = (_Float16)v;
    return;
  }
  if (blk < 1280) {                             // pack Wdh
    int id = (blk - 1024)*256 + tid;            // [32][4][64][8]
    int j = id & 7, l = (id>>3)&63, ks = (id>>9)&3, c = id>>11;
    int row = c*16 + (l&15);
    int k   = ks*32 + ((l>>4)&3)*8 + j;
    ((_Float16*)(ws + OFF_WD))[id] = (_Float16)Wdh[row*128 + k];
    return;
  }
  if (blk < 7424) {                             // pack gates [32][4][24][64][8]
    int id = (blk - 1280)*256 + tid;
    int j = id & 7, l = (id>>3)&63;
    int f = id>>9;
    int ks = f % 24; f /= 24;
    int g = f & 3, c = f >> 2;
    int rn = g*512 + c*16 + (l&15);
    int k  = ks*32 + ((l>>4)&3)*8 + j;
    float v = (k < 256) ? W_ih[rn*256 + k] : W_hh[rn*512 + (k-256)];
    ((_Float16*)(ws + OFF_GB))[id] = (_Float16)v;
    return;
  }
  {                                             // bias
    int id = (blk - 7424)*256 + tid;            // 2048
    ((float*)(ws + OFF_BG))[id] = b_ih[id] + b_hh[id];
  }
}

// ---------------- main persistent kernel ----------------

__global__ __launch_bounds__(256, 1) void brits_main(
    const float* __restrict__ data,
    const float* __restrict__ bh,
    const float* __restrict__ bfv,
    const float* __restrict__ bdh,
    unsigned char* __restrict__ ws,
    float* __restrict__ out)
{
  const int bt  = blockIdx.x & 7;     // batch tile (== XCD under round-robin)
  const int ch  = blockIdx.x >> 3;    // H chunk 0..31
  const int tid = threadIdx.x;
  const int wv  = tid >> 6;           // wave 0..3
  const int ln  = tid & 63;
  const int l15 = ln & 15;
  const int lq  = ln >> 4;

  _Float16*       hbuf = (_Float16*)(ws + OFF_HBUF);
  unsigned int*   tag  = (unsigned int*)(ws + OFF_TAG);
  unsigned int*   dflg = (unsigned int*)(ws + OFF_DFLG);
  unsigned int*   dsnt = (unsigned int*)(ws + OFF_DSNT);
  unsigned int*   dsn2 = (unsigned int*)(ws + OFF_DSN2);
  const float*    msum = (const float*)(ws + OFF_MSUM);
  const float*    bgq  = (const float*)(ws + OFF_BG);
  const f16x8*    WhP  = (const f16x8*)(ws + OFF_WH);
  const f16x8*    WfP  = (const f16x8*)(ws + OFF_WF);
  const f16x8*    WdP  = (const f16x8*)(ws + OFF_WD);
  const f16x8*    GBP  = (const f16x8*)(ws + OFF_GB);
  const _Float16* dbf  = (const _Float16*)(ws + OFF_DBF);

  __shared__ __align__(16) _Float16 xcT[16][136];
  __shared__ __align__(16) _Float16 ccT[16][136];
  __shared__ __align__(8)  _Float16 hstg[16][16];
  __shared__ __align__(16) _Float16 hstage[8192];    // tier-1 staging (16KB)
  __shared__ unsigned int sbounce[4][64];
  __shared__ float ccF[16][132];                     // fp32 c_c for out-stores
  __shared__ float gbuf[4][16][17];                  // +1 pad: kill 4-way conflicts
  __shared__ float cst[16][17];
  __shared__ float invms[256];
  __shared__ float bh_s[128], bf_s[128], bdh_s[16], bg_s[4][16];
  __shared__ float red[256];
  __shared__ int sNT[4], sB[4];

  unsigned int* myflg  = dflg + ((bt<<5) + ch)*16;
  unsigned int* mysnt  = dsnt + ((bt<<5) + ch)*16;
  unsigned int* mysnt2 = dsn2 + ((bt<<5) + ch)*16;
  const unsigned int* pollflg  = dflg + ((bt<<5) + (ln & 31))*16;
  const unsigned int* sntslot  = dsnt + ((bt<<5) + (ln & 31))*16;
  const unsigned int* snt2slot = dsn2 + ((bt<<5) + (ln & 31))*16;

  auto gate = [&](unsigned thr){
    for (;;) {
      bool ok = true;
      if (ln < 32)
        ok = (__hip_atomic_load(pollflg, __ATOMIC_RELAXED,
                                __HIP_MEMORY_SCOPE_AGENT) & 15u) >= thr;
      if (__ballot(ok) == ~0ull) break;
      __builtin_amdgcn_s_sleep(8);
    }
  };
  auto setf = [&](unsigned v){
    if (tid == 0)
      __hip_atomic_store(myflg, v, __ATOMIC_RELAXED, __HIP_MEMORY_SCOPE_AGENT);
  };
  auto sentinel_write = [&](unsigned int* p, unsigned v, unsigned flagv){
    if (tid == 0) {
      *p = v;                                        // plain store -> own-XCD L2
      __asm__ __volatile__("" ::: "memory");
      __builtin_amdgcn_s_waitcnt(0);
      __hip_atomic_store(myflg, flagv, __ATOMIC_RELAXED, __HIP_MEMORY_SCOPE_AGENT);
    }
  };

  // ---------- tier-0 (nt) double-sentinel ----------
  sentinel_write(mysnt2, 0xC3000000u | (unsigned)(bt<<8) | (unsigned)ch, 1u);
  gate(1);
  bool nt1;
  { unsigned v = 0;
    if (ln < 32) v = __builtin_nontemporal_load(snt2slot);
    __asm__ __volatile__("" ::: "memory");
    nt1 = (__ballot(ln >= 32 ||
                    v == (0xC3000000u | (unsigned)(bt<<8) | (unsigned)(ln & 31))) == ~0ull); }
  __syncthreads();
  setf(2); gate(2);                                  // all blocks done phase-1 reads
  sentinel_write(mysnt2, 0x3C000000u | (unsigned)(bt<<8) | (unsigned)ch, 3u);
  gate(3);
  bool nt2;
  { unsigned v = 0;
    if (ln < 32) v = __builtin_nontemporal_load(snt2slot);
    __asm__ __volatile__("" ::: "memory");
    nt2 = (__ballot(ln >= 32 ||
                    v == (0x3C000000u | (unsigned)(bt<<8) | (unsigned)(ln & 31))) == ~0ull); }
  __syncthreads();
  setf(4); gate(4);
  // ---------- tier-1 (sc0 bounce) double-sentinel ----------
  sentinel_write(mysnt, 0xA5000000u | (unsigned)(bt<<8) | (unsigned)ch, 5u);
  gate(5);
  bool b1;
  { if (ln < 32)
      __builtin_amdgcn_global_load_lds((const AS1 void*)sntslot,
          (AS3 void*)&sbounce[wv][0], 4, 0, 1 /*sc0*/);
    __asm__ __volatile__("" ::: "memory");
    __builtin_amdgcn_s_waitcnt(0);
    __asm__ __volatile__("" ::: "memory");
    b1 = (__ballot(ln >= 32 ||
                   sbounce[wv][ln] == (0xA5000000u | (unsigned)(bt<<8) | (unsigned)(ln & 31))) == ~0ull); }
  __syncthreads();
  setf(6); gate(6);
  sentinel_write(mysnt, 0x5A000000u | (unsigned)(bt<<8) | (unsigned)ch, 7u);
  gate(7);
  bool b2;
  { if (ln < 32)
      __builtin_amdgcn_global_load_lds((const AS1 void*)sntslot,
          (AS3 void*)&sbounce[wv][0], 4, 0, 1 /*sc0*/);
    __asm__ __volatile__("" ::: "memory");
    __builtin_amdgcn_s_waitcnt(0);
    __asm__ __volatile__("" ::: "memory");
    b2 = (__ballot(ln >= 32 ||
                   sbounce[wv][ln] == (0x5A000000u | (unsigned)(bt<<8) | (unsigned)(ln & 31))) == ~0ull); }
  __syncthreads();
  if (ln == 0) { sNT[wv] = (nt1 && nt2) ? 1 : 0; sB[wv] = (b1 && b2) ? 1 : 0; }
  __syncthreads();
  if (tid == 0) {
    unsigned f = 8u;
    if (sNT[0] && sNT[1] && sNT[2] && sNT[3]) f |= 16u;
    if (sB[0]  && sB[1]  && sB[2]  && sB[3])  f |= 32u;
    __hip_atomic_store(myflg, f, __ATOMIC_RELAXED, __HIP_MEMORY_SCOPE_AGENT);
  }
  int mode;                                          // 0=nt, 1=bounce, 2=UC (tile-uniform)
  { unsigned v = 0;
    for (;;) {
      bool ok = true;
      if (ln < 32) {
        v = __hip_atomic_load(pollflg, __ATOMIC_RELAXED, __HIP_MEMORY_SCOPE_AGENT);
        ok = (v & 15u) >= 8u;
      }
      if (__ballot(ok) == ~0ull) break;
      __builtin_amdgcn_s_sleep(8);
    }
    bool allnt = (__ballot(ln >= 32 || (v & 16u)) == ~0ull);
    bool allb  = (__ballot(ln >= 32 || (v & 32u)) == ~0ull);
    mode = allnt ? 0 : (allb ? 1 : 2);
  }

  invms[tid] = 1.0f / (msum[tid] + 1e-5f);
  if (tid < 128) { bh_s[tid] = bh[tid]; bf_s[tid] = bfv[tid]; }
  if (tid < 16)  bdh_s[tid] = bdh[ch*16 + tid];
  if (tid < 64)  bg_s[tid>>4][tid&15] = bgq[(tid>>4)*512 + ch*16 + (tid&15)];
  for (int z = tid; z < 272; z += 256) ((float*)cst)[z] = 0.0f;
  __syncthreads();

  // ---- persistent weight fragments in VGPRs ----
  f16x8 WhB[2][16], WfB[2][4], GB[24], WdB[4];
  #pragma unroll
  for (int i=0;i<2;i++)
    #pragma unroll
    for (int ks=0;ks<16;ks++)
      WhB[i][ks] = WhP[((2*wv+i)*16 + ks)*64 + ln];
  #pragma unroll
  for (int i=0;i<2;i++)
    #pragma unroll
    for (int ks=0;ks<4;ks++)
      WfB[i][ks] = WfP[((2*wv+i)*4 + ks)*64 + ln];
  #pragma unroll
  for (int ks=0;ks<24;ks++)
    GB[ks] = GBP[((ch*4 + wv)*24 + ks)*64 + ln];
  #pragma unroll
  for (int ks=0;ks<4;ks++)
    WdB[ks] = WdP[(ch*4 + ks)*64 + ln];

  float loss_acc = 0.0f;
  const int rowg = bt*16;

  // producer store address (fragment-order layout), 8B = 4 cols of one row
  const int prow = ln >> 2;
  const int pc0  = ch*16 + (ln & 3)*4;
  const size_t pelem = ((size_t)((pc0 >> 5)*64 + ((pc0 >> 3) & 3)*16 + prow))*8 + (pc0 & 7);
  unsigned int* tagw = tag + ((bt<<5) + ch)*16;
  const unsigned int* tagslot = tag + ((bt<<5) + (ln & 31))*16;

  #pragma unroll 1
  for (int t = 0; t < 256; ++t) {
    // ---- prefetch everything that doesn't depend on h(t) ----
    float xnv[2][4], mmv[2][4];
    #pragma unroll
    for (int i=0;i<2;i++){
      int col = (2*wv+i)*16 + l15;
      #pragma unroll
      for (int r=0;r<4;r++){
        float dv = data[((rowg + lq*4 + r)*256 + t)*128 + col];
        bool ok = (dv == dv);
        xnv[i][r] = ok ? dv : 0.0f;
        mmv[i][r] = ok ? 1.0f : 0.0f;
      }
    }
    f16x8 mA[4];
    {
      const float* mrow = data + ((size_t)(rowg + l15)*256 + t)*128 + lq*8;
      #pragma unroll
      for (int k=0;k<4;k++){
        float4 a0 = *(const float4*)(mrow + k*32);
        float4 a1 = *(const float4*)(mrow + k*32 + 4);
        f16x8 mv;
        mv[0] = (a0.x==a0.x)?(_Float16)1.0f:(_Float16)0.0f;
        mv[1] = (a0.y==a0.y)?(_Float16)1.0f:(_Float16)0.0f;
        mv[2] = (a0.z==a0.z)?(_Float16)1.0f:(_Float16)0.0f;
        mv[3] = (a0.w==a0.w)?(_Float16)1.0f:(_Float16)0.0f;
        mv[4] = (a1.x==a1.x)?(_Float16)1.0f:(_Float16)0.0f;
        mv[5] = (a1.y==a1.y)?(_Float16)1.0f:(_Float16)0.0f;
        mv[6] = (a1.z==a1.z)?(_Float16)1.0f:(_Float16)0.0f;
        mv[7] = (a1.w==a1.w)?(_Float16)1.0f:(_Float16)0.0f;
        mA[k] = mv;
      }
    }
    // gamma_h(t+1) pre-activation: h-independent, hoisted into the wait window
    f32x4 ga = {0.f,0.f,0.f,0.f};
    if (wv == 0 && t < 255) {
      f16x8 dA[4];
      #pragma unroll
      for (int k=0;k<4;k++)
        dA[k] = *(const f16x8*)(dbf + ((size_t)(rowg+l15)*256 + (t+1))*128 + k*32 + lq*8);
      #pragma unroll
      for (int k=0;k<4;k++)
        ga = __builtin_amdgcn_mfma_f32_16x16x32_f16(dA[k], WdB[k], ga, 0,0,0);
    }

    // ---- wait for h(t) ----
    if (t > 0) {
      if (mode == 0) {
        for (;;) {
          unsigned tv = 0;
          if (ln < 32) tv = __builtin_nontemporal_load(tagslot);
          __asm__ __volatile__("" ::: "memory");
          if (__ballot(ln >= 32 || tv >= (unsigned)t) == ~0ull) break;
          __builtin_amdgcn_s_sleep(1);
        }
      } else if (mode == 1) {
        for (;;) {
          if (ln < 32)
            __builtin_amdgcn_global_load_lds((const AS1 void*)tagslot,
                (AS3 void*)&sbounce[wv][0], 4, 0, 1 /*sc0*/);
          __asm__ __volatile__("" ::: "memory");
          __builtin_amdgcn_s_waitcnt(0);
          __asm__ __volatile__("" ::: "memory");
          bool ok = true;
          if (ln < 32) ok = sbounce[wv][ln] >= (unsigned)t;
          if (__ballot(ok) == ~0ull) break;
          __builtin_amdgcn_s_sleep(1);
        }
      } else {
        for (;;) {
          bool ok = true;
          if (ln < 32)
            ok = __hip_atomic_load(tagslot, __ATOMIC_RELAXED,
                                   __HIP_MEMORY_SCOPE_AGENT) >= (unsigned)t;
          if (__ballot(ok) == ~0ull) break;
          __builtin_amdgcn_s_sleep(1);
        }
      }
    }

    // ---- h A-fragments ----
    f16x8 hA[16];
    const char* hbB = (const char*)hbuf + (size_t)(((t&1)*8 + bt))*16384;
    if (mode == 0) {
      // direct nt loads: fragment-order layout is lane-linear (ln*16 per ks)
      #pragma unroll
      for (int ks=0;ks<16;ks++) {
        u32x4 hv = __builtin_nontemporal_load((const u32x4*)(hbB + ks*1024 + ln*16));
        hA[ks] = __builtin_bit_cast(f16x8, hv);
      }
    } else if (mode == 1) {
      #pragma unroll
      for (int s=0;s<4;s++){
        int off = s*4096 + wv*1024;
        __builtin_amdgcn_global_load_lds((const AS1 void*)(hbB + off + ln*16),
            (AS3 void*)((char*)hstage + off), 16, 0, 1 /*sc0*/);
      }
      __asm__ __volatile__("" ::: "memory");
      __builtin_amdgcn_s_waitcnt(0);
      __syncthreads();
      #pragma unroll
      for (int ks=0;ks<16;ks++)
        hA[ks] = *(const f16x8*)((const char*)hstage + ks*1024 + ln*16);
    } else {
      #pragma unroll
      for (int ks=0;ks<16;ks++) {
        const char* p = hbB + (size_t)(ks*64 + ln)*16;
        union { unsigned long long u[2]; f16x8 v; } cv;
        cv.u[0] = __hip_atomic_load((const unsigned long long*)p,
                                    __ATOMIC_RELAXED, __HIP_MEMORY_SCOPE_AGENT);
        cv.u[1] = __hip_atomic_load((const unsigned long long*)(p + 8),
                                    __ATOMIC_RELAXED, __HIP_MEMORY_SCOPE_AGENT);
        hA[ks] = cv.v;
      }
    }

    // ---- x_h = sigmoid(h @ Wh^T + bh); loss1; x_c ----
    float xhv[2][4];
    float numer = 0.0f;
    #pragma unroll
    for (int i=0;i<2;i++){
      f32x4 a0 = {0.f,0.f,0.f,0.f}, a1 = {0.f,0.f,0.f,0.f};
      #pragma unroll
      for (int ks=0;ks<8;ks++){
        a0 = __builtin_amdgcn_mfma_f32_16x16x32_f16(hA[ks],   WhB[i][ks],   a0, 0,0,0);
        a1 = __builtin_amdgcn_mfma_f32_16x16x32_f16(hA[ks+8], WhB[i][ks+8], a1, 0,0,0);
      }
      int col = (2*wv+i)*16 + l15;
      float bhc = bh_s[col];
      #pragma unroll
      for (int r=0;r<4;r++){
        float s = sigm(a0[r] + a1[r] + bhc);
        xhv[i][r] = s;
        numer += fabsf(xnv[i][r] - s) * mmv[i][r];
        float xc = (mmv[i][r] > 0.f) ? xnv[i][r] : s;
        xcT[lq*4 + r][col] = (_Float16)xc;
      }
    }
    __syncthreads();

    // ---- z_h MFMAs + gate partials (h & m parts) interleaved ----
    f16x8 xcA[4];
    #pragma unroll
    for (int k=0;k<4;k++)
      xcA[k] = *(const f16x8*)(&xcT[l15][k*32 + lq*8]);
    f32x4 z0 = {0.f,0.f,0.f,0.f}, z1 = {0.f,0.f,0.f,0.f};
    #pragma unroll
    for (int ks=0;ks<4;ks++){
      z0 = __builtin_amdgcn_mfma_f32_16x16x32_f16(xcA[ks], WfB[0][ks], z0, 0,0,0);
      z1 = __builtin_amdgcn_mfma_f32_16x16x32_f16(xcA[ks], WfB[1][ks], z1, 0,0,0);
    }
    f32x4 g0 = {0.f,0.f,0.f,0.f}, g1 = {0.f,0.f,0.f,0.f};
    #pragma unroll
    for (int k=0;k<4;k++){
      g0 = __builtin_amdgcn_mfma_f32_16x16x32_f16(mA[k],   GB[4+k],  g0, 0,0,0);
      g1 = __builtin_amdgcn_mfma_f32_16x16x32_f16(hA[k+8], GB[16+k], g1, 0,0,0);
    }
    #pragma unroll
    for (int ks=0;ks<8;ks++)
      g0 = __builtin_amdgcn_mfma_f32_16x16x32_f16(hA[ks], GB[8+ks], g0, 0,0,0);
    #pragma unroll
    for (int ks=4;ks<8;ks++)
      g1 = __builtin_amdgcn_mfma_f32_16x16x32_f16(hA[ks+8], GB[16+ks], g1, 0,0,0);

    // ---- z_h epilogue: loss2, c_c (fp32 to ccF, f16 to ccT) ----
    #pragma unroll
    for (int i=0;i<2;i++){
      f32x4 a = (i==0) ? z0 : z1;
      int col = (2*wv+i)*16 + l15;
      float bfc = bf_s[col];
      #pragma unroll
      for (int r=0;r<4;r++){
        float z = sigm(a[r] + bfc);
        numer += fabsf(xnv[i][r] - z) * mmv[i][r];
        float chv = fabsf(0.5f*z + 0.5f*xhv[i][r]);
        float cc  = (mmv[i][r] > 0.f) ? xnv[i][r] : chv;
        int row = lq*4 + r;
        ccT[row][col] = (_Float16)cc;
        ccF[row][col] = cc;
      }
    }
    if (ch == 0) loss_acc += numer * invms[t];
    __syncthreads();

    // ---- gates: add c_c part, reduce, stash ----
    f16x8 ccA[4];
    #pragma unroll
    for (int k=0;k<4;k++)
      ccA[k] = *(const f16x8*)(&ccT[l15][k*32 + lq*8]);
    #pragma unroll
    for (int k=0;k<4;k++)
      g0 = __builtin_amdgcn_mfma_f32_16x16x32_f16(ccA[k], GB[k], g0, 0,0,0);
    #pragma unroll
    for (int r=0;r<4;r++) gbuf[wv][lq*4 + r][l15] = g0[r] + g1[r];
    __syncthreads();

    // ---- post-barrier: out-stores (wave1, fire-and-forget into next poll
    //      window) + LSTM epilogue / h store / tag (wave0) ----
    if (wv == 1) {
      // this block's 4 imputation cols (exact fp32), 64 values
      int row = ln >> 2, col = ch*4 + (ln & 3);
      out[1 + ((size_t)(rowg+row)*256 + t)*128 + col] = ccF[row][col];
    }
    if (wv == 0) {
      #pragma unroll
      for (int r=0;r<4;r++){
        int row = lq*4 + r;
        float ii = gbuf[0][row][l15] + bg_s[0][l15];
        float ff = gbuf[1][row][l15] + bg_s[1][l15];
        float gg = gbuf[2][row][l15] + bg_s[2][l15];
        float oo = gbuf[3][row][l15] + bg_s[3][l15];
        float co = cst[row][l15];
        float cn = sigm(ff)*co + sigm(ii)*tanh_(gg);
        cst[row][l15] = cn;
        if (t < 255) {
          float hn = sigm(oo)*tanh_(cn);
          float gh = __expf(-fmaxf(ga[r] + bdh_s[l15], 0.0f));
          hstg[row][l15] = (_Float16)(hn * gh);
        }
      }
      if (t < 255) {
        __asm__ __volatile__("" ::: "memory");
        unsigned long long v = *(const unsigned long long*)&hstg[prow][(ln & 3)*4];
        char* dp = (char*)hbuf + (size_t)((((t+1)&1)*8 + bt))*16384 + pelem*2;
        unsigned tv = (unsigned)(t+1);
        if (mode < 2) {
          *(unsigned long long*)dp = v;               // plain store -> own-XCD L2
          __asm__ __volatile__("" ::: "memory");
          __builtin_amdgcn_s_waitcnt(0);              // h in L2 before tag
          __asm__ __volatile__("" ::: "memory");
          if (ln == 0) tagw[0] = tv;                  // plain tag store
          __asm__ __volatile__("" ::: "memory");
        } else {
          __hip_atomic_store((unsigned long long*)dp, v,
                             __ATOMIC_RELAXED, __HIP_MEMORY_SCOPE_AGENT);
          __atomic_signal_fence(__ATOMIC_SEQ_CST);
          __builtin_amdgcn_s_waitcnt(0);
          __atomic_signal_fence(__ATOMIC_SEQ_CST);
          if (ln == 0)
            __hip_atomic_store(tagw, tv,
                               __ATOMIC_RELAXED, __HIP_MEMORY_SCOPE_AGENT);
        }
      }
    }
  }

  // ---- loss reduction (chunk-0 blocks only) ----
  if (ch == 0) {
    red[tid] = loss_acc;
    __syncthreads();
    if (tid == 0) {
      float s = 0.f;
      for (int i=0;i<256;i++) s += red[i];
      atomicAdd(out, 0.3f * s);
    }
  }
}

// ---------------- launch ----------------

extern "C" void kernel_launch(void* const* d_in, const int* in_sizes, int n_in,
                              void* d_out, int out_size, void* d_ws, size_t ws_size,
                              hipStream_t stream) {
  const float* data = (const float*)d_in[0];
  const float* W_ih = (const float*)d_in[1];
  const float* b_ih = (const float*)d_in[2];
  const float* W_hh = (const float*)d_in[3];
  const float* b_hh = (const float*)d_in[4];
  const float* Wdh  = (const float*)d_in[5];
  const float* bdh  = (const float*)d_in[6];
  // d_in[7] Wdx, d_in[8] bdx: dead code in reference forward
  const float* Wh   = (const float*)d_in[9];
  const float* bh   = (const float*)d_in[10];
  const float* Wf   = (const float*)d_in[11];
  const float* bf   = (const float*)d_in[12];
  // d_in[13] Wc, d_in[14] bc: dead code
  float* out = (float*)d_out;
  unsigned char* ws = (unsigned char*)d_ws;

  k_prep     <<<7432, 256, 0, stream>>>(data, W_ih, W_hh, Wdh, Wh, Wf,
                                        b_ih, b_hh, ws, out);
  brits_main <<<256,  256, 0, stream>>>(data, bh, bf, bdh, ws, out);
}